// Round 6
// baseline (128.944 us; speedup 1.0000x reference)
//
#include <hip/hip_runtime.h>
#include <stdint.h>

#define NROWS 8192
#define KDIM  512
#define BM    128
#define BK    32
#define NT    (NROWS / BM)                  // 64 tiles per dim
#define NKT   (KDIM / BK)                   // 16 k-tiles

typedef __attribute__((ext_vector_type(8))) short bf16x8;
typedef __attribute__((ext_vector_type(4))) float f32x4;

__device__ __forceinline__ unsigned short f32_to_bf16(float f) {
  union { float f; unsigned int u; } v; v.f = f;
  unsigned int u = v.u;
  u += 0x7FFFu + ((u >> 16) & 1u);   // round-to-nearest-even
  return (unsigned short)(u >> 16);
}

__device__ __forceinline__ void async_copy16(const unsigned short* g, unsigned short* l) {
  __builtin_amdgcn_global_load_lds(
      (const __attribute__((address_space(1))) unsigned int*)g,
      (__attribute__((address_space(3))) unsigned int*)l,
      16, 0, 0);
}

// Kernel 1: row-normalize fp32 -> bf16 (RNE), PRE-SWIZZLED output layout.
// Within each row, global 16B k-chunk g is stored at position g ^ ((row>>1)&3)
// (permutation inside aligned 64B windows): sim kernel reads lane-linear
// (coalesced; R2: permuted global reads cost +44us) and LDS lands
// bank-conflict-free (R1/R3: conflicts 4.26M -> 0).
__global__ __launch_bounds__(128) void prep_kernel(
    const float* __restrict__ src, unsigned short* __restrict__ dst,
    float* __restrict__ acc) {
  const int row = blockIdx.x;
  const int tid = threadIdx.x;
  const float4 v = ((const float4*)src)[row * 128 + tid];
  float ss = v.x * v.x + v.y * v.y + v.z * v.z + v.w * v.w;
  #pragma unroll
  for (int off = 32; off > 0; off >>= 1) ss += __shfl_down(ss, off);
  __shared__ float red[2];
  __shared__ float s_rn;
  const int lane = tid & 63, w = tid >> 6;
  if (lane == 0) red[w] = ss;
  __syncthreads();
  if (tid == 0) {
    s_rn = 1.0f / sqrtf(red[0] + red[1]);   // norms ~22.6, EPS can never fire
    if (row == 0) *acc = 0.0f;
  }
  __syncthreads();
  const float rn = s_rn;
  ushort4 o;
  o.x = f32_to_bf16(v.x * rn);
  o.y = f32_to_bf16(v.y * rn);
  o.z = f32_to_bf16(v.z * rn);
  o.w = f32_to_bf16(v.w * rn);
  const int cg   = tid >> 1;                       // 16B chunk index 0..63
  const int xorv = (row >> 1) & 3;
  const int p    = (cg & 0x3C) | ((cg & 3) ^ xorv);
  ((ushort4*)dst)[row * 128 + p * 2 + (tid & 1)] = o;
}

// Kernel 2: tiled bf16 MFMA GEMM (idn @ idn^T) fused with clamp, diagonal
// masking, and full reduction. 2D grid (XCD = bj%8 -> B-set L2-resident).
// Upper-tri blocks only; strictly-upper 2x.
//
// R5: ZERO-BARRIER K-loop. Each wave stages its own private A-half/B-half
// (64 rows x BK) into its own LDS region, double-buffered; synchronization
// is s_waitcnt vmcnt(8) only. No s_barrier -> no wave convoy; all LDS
// hazards are wave-local (program order + counters). Staged L2 traffic 2x
// (halves shared across wave pairs are duplicated) -- L2 has 4x headroom.
__global__ __launch_bounds__(256) void sim_reduce_kernel(
    const unsigned short* __restrict__ idn, float* __restrict__ acc) {
  const int bi = blockIdx.y;
  const int bj = blockIdx.x;
  if (bj < bi) return;               // block-uniform early exit (dead block)

  // 4 waves x 2 stages x (A 2048 shorts + B 2048 shorts) = 64 KB
  __shared__ __align__(16) unsigned short smem[4 * 2 * 4096];

  const int tid  = threadIdx.x;      // 0..255, 4 waves
  const int lane = tid & 63;
  const int w    = tid >> 6;
  const int wr   = (w >> 1) * 64;    // wave's 64x64 quadrant
  const int wc   = (w & 1) * 64;
  const int q    = lane >> 4;        // k-chunk this lane needs (0..3)
  const int r16  = lane & 15;
  const int koff = (q ^ ((r16 >> 1) & 3)) * 8;   // deswizzle on LDS read (shorts)

  // wave-private stage bases (shorts)
  unsigned short* stg[2] = { smem + (w * 2 + 0) * 4096, smem + (w * 2 + 1) * 4096 };
  // within a stage: A at +0 (64 rows x 32k, chunk c=row*4+pos at c*8),
  //                 B at +2048 (same layout)

  f32x4 acc_f[4][4];
  #pragma unroll
  for (int i = 0; i < 4; i++)
    #pragma unroll
    for (int j = 0; j < 4; j++)
      acc_f[i][j] = (f32x4){0.f, 0.f, 0.f, 0.f};

  // Global fill pointers: inst j covers local rows [j*16, j*16+16), 4 lanes
  // per row, (lane&3) selecting the 16B chunk within the 64B k-window --
  // identical 16-line coalescing to R0/R3. Memory is pre-swizzled, so
  // lane-linear reads land the deswizzle-ready chunk order in LDS.
  const unsigned short* gA[4];
  const unsigned short* gB[4];
  #pragma unroll
  for (int j = 0; j < 4; j++) {
    const int rA = bi * BM + wr + j * 16 + (lane >> 2);
    const int rB = bj * BM + wc + j * 16 + (lane >> 2);
    gA[j] = idn + rA * KDIM + (lane & 3) * 8;
    gB[j] = idn + rB * KDIM + (lane & 3) * 8;
  }
  const int ldst = lane * 8;         // lane-linear LDS dest (shorts)

  // prologue: stage tile 0 into stage 0
  #pragma unroll
  for (int j = 0; j < 4; j++) async_copy16(gA[j], stg[0] + j * 512 + ldst);
  #pragma unroll
  for (int j = 0; j < 4; j++) async_copy16(gB[j], stg[0] + 2048 + j * 512 + ldst);

  #pragma unroll
  for (int t = 0; t < NKT; ++t) {
    const int cs = t & 1;
    if (t + 1 < NKT) {
      const int ns = cs ^ 1;
      const int ko = (t + 1) * BK;
      #pragma unroll
      for (int j = 0; j < 4; j++)
        async_copy16(gA[j] + ko, stg[ns] + j * 512 + ldst);
      #pragma unroll
      for (int j = 0; j < 4; j++)
        async_copy16(gB[j] + ko, stg[ns] + 2048 + j * 512 + ldst);
      asm volatile("s_waitcnt vmcnt(8)" ::: "memory");  // tile t landed; t+1 in flight
    } else {
      asm volatile("s_waitcnt vmcnt(0)" ::: "memory");
    }

    bf16x8 a[4], b[4];
    #pragma unroll
    for (int mi = 0; mi < 4; mi++)   // A frag: local row = mi*16+r16, offset row*32+koff
      a[mi] = *(const bf16x8*)&stg[cs][(mi * 16 + r16) * 32 + koff];
    #pragma unroll
    for (int ni = 0; ni < 4; ni++)
      b[ni] = *(const bf16x8*)&stg[cs][2048 + (ni * 16 + r16) * 32 + koff];
    #pragma unroll
    for (int mi = 0; mi < 4; mi++)
      #pragma unroll
      for (int ni = 0; ni < 4; ni++)
        acc_f[mi][ni] = __builtin_amdgcn_mfma_f32_16x16x32_bf16(
            a[mi], b[ni], acc_f[mi][ni], 0, 0, 0);
  }

  // Epilogue: clamp at zero, mask diagonal, reduce.
  // C/D layout (verified m89/m91): col = lane&15, row = (lane>>4)*4 + reg.
  float local = 0.f;
  const bool diag = (bi == bj);
  #pragma unroll
  for (int mi = 0; mi < 4; mi++)
    #pragma unroll
    for (int ni = 0; ni < 4; ni++)
      #pragma unroll
      for (int rr = 0; rr < 4; rr++) {
        const int ri = wr + mi * 16 + q * 4 + rr;
        const int ci = wc + ni * 16 + r16;
        float v = fmaxf(acc_f[mi][ni][rr], 0.f);
        if (diag && ri == ci) v = 0.f;
        local += v;
      }

  #pragma unroll
  for (int off = 32; off > 0; off >>= 1) local += __shfl_down(local, off);
  __syncthreads();                   // staging dead; reuse smem for reduce
  float* red = (float*)smem;
  if (lane == 0) red[w] = local;
  __syncthreads();
  if (tid == 0) {
    float s = red[0] + red[1] + red[2] + red[3];
    if (!diag) s *= 2.f;             // strictly-upper tiles cover both triangles
    atomicAdd(acc, s);
  }
}

// Kernel 3: scale and write both outputs (total_loss == l_id_div, DIV_COEF=1).
__global__ void finalize_kernel(const float* __restrict__ acc, float* __restrict__ out) {
  const float m = *acc * (1.0f / ((float)NROWS * (float)NROWS));
  out[0] = m;
  out[1] = m;
}

extern "C" void kernel_launch(void* const* d_in, const int* in_sizes, int n_in,
                              void* d_out, int out_size, void* d_ws, size_t ws_size,
                              hipStream_t stream) {
  const float* id = (const float*)d_in[0];
  float* out = (float*)d_out;
  unsigned short* idn = (unsigned short*)d_ws;                     // 8 MB bf16
  float* acc = (float*)((char*)d_ws + (size_t)NROWS * KDIM * 2);

  prep_kernel<<<NROWS, 128, 0, stream>>>(id, idn, acc);
  dim3 grid(NT, NT);
  sim_reduce_kernel<<<grid, 256, 0, stream>>>(idn, acc);
  finalize_kernel<<<1, 1, 0, stream>>>(acc, out);
}